// Round 11
// baseline (174.388 us; speedup 1.0000x reference)
//
#include <hip/hip_runtime.h>
#include <hip/hip_bf16.h>
#include <math.h>

#define B_ 2
#define T_ 2048
#define C_ 1024
#define H_ 16
#define HKV_ 4
#define G_ 4
#define HD_ 64
#define KVC_ 256      // HKV*HD
#define NQKV_ 1536    // C_ + 2*KVC_
#define NQT_ 32       // T_/64 q-tiles

typedef __attribute__((ext_vector_type(8))) short bf16x8;
typedef __attribute__((ext_vector_type(4))) float f32x4;

static __device__ inline short f2bf(float f) {          // RNE (off hot path)
    __hip_bfloat16 h = __float2bfloat16(f);
    short s;
    __builtin_memcpy(&s, &h, 2);
    return s;
}
static __device__ inline short f2bf_trunc(float f) {    // RTZ, 1 op (hot path)
    unsigned int u;
    __builtin_memcpy(&u, &f, 4);
    return (short)(u >> 16);
}
static __device__ inline float bf2f(short s) {
    unsigned int u = ((unsigned int)(unsigned short)s) << 16;
    float f;
    __builtin_memcpy(&f, &u, 4);
    return f;
}

// async global->LDS, 16B per lane; lds base wave-uniform, dest = base + lane*16.
static __device__ inline void gload_lds16(const short* g, short* lds) {
    __builtin_amdgcn_global_load_lds(
        (const __attribute__((address_space(1))) unsigned int*)g,
        (__attribute__((address_space(3))) unsigned int*)lds, 16, 0, 0);
}

// ---------------- elementwise fp32 -> bf16 cast (8 elems/thread) ----------
__global__ __launch_bounds__(256) void cast_bf16(
    const float* __restrict__ in, short* __restrict__ out, int n)
{
    const int i = (blockIdx.x * 256 + threadIdx.x) * 8;
    if (i >= n) return;
    const float4 a = *(const float4*)(in + i);
    const float4 b = *(const float4*)(in + i + 4);
    bf16x8 o;
    o[0] = f2bf(a.x); o[1] = f2bf(a.y); o[2] = f2bf(a.z); o[3] = f2bf(a.w);
    o[4] = f2bf(b.x); o[5] = f2bf(b.y); o[6] = f2bf(b.z); o[7] = f2bf(b.w);
    *(bf16x8*)(out + i) = o;
}

// ------------- fused weight transpose+cast (z selects matrix) -------------
__global__ __launch_bounds__(256) void w_transpose(
    const float* __restrict__ Wq, const float* __restrict__ Wk,
    const float* __restrict__ Wv, const float* __restrict__ Wo,
    short* __restrict__ Wt, short* __restrict__ Wot)
{
    const int z = blockIdx.z;
    const float* in;
    short* out;
    int N;
    if (z == 0)      { in = Wq; out = Wt;                     N = C_; }
    else if (z == 1) { in = Wk; out = Wt + C_ * C_;           N = KVC_; }
    else if (z == 2) { in = Wv; out = Wt + (C_ + KVC_) * C_;  N = KVC_; }
    else             { in = Wo; out = Wot;                    N = C_; }
    const int n0 = blockIdx.x * 32;
    if (n0 >= N) return;
    __shared__ float t[32][33];
    const int tx = threadIdx.x, ty = threadIdx.y;     // 32 x 8
    const int k0 = blockIdx.y * 32;
    #pragma unroll
    for (int j = 0; j < 4; j++)
        t[ty + j * 8][tx] = in[(size_t)(k0 + ty + j * 8) * N + n0 + tx];
    __syncthreads();
    #pragma unroll
    for (int j = 0; j < 4; j++)
        out[(size_t)(n0 + ty + j * 8) * C_ + k0 + tx] = f2bf(t[tx][ty + j * 8]);
}

// ------- bf16 MFMA GEMM: 128x128 tile, BK=32, 3-buffer 2-deep prefetch ----
// T4 counted-vmcnt pipeline: stage K-step t+2 while computing t; wait only
// for t+1's 4 loads (vmcnt(4), never 0 mid-loop) so TWO compute phases
// cover the ~500-700cy load latency that the old 2-phase vmcnt(0) drain
// exposed every step (gemm grids are only 1-1.5 blocks/CU: no inter-block
// cover). Rotation hazard: stage of buf (t+2)%3 overwrites data last read
// at t-1, which completed before that step's end barrier.
template <bool OUT_BF16>
__global__ __launch_bounds__(256) void gemm_bf16(
    const short* __restrict__ A, const short* __restrict__ Bt,
    void* __restrict__ Cout, int M, int N, int K)
{
    __shared__ short As[3][128 * 32];
    __shared__ short Bs[3][128 * 32];
    const int tid = threadIdx.x;
    const int wave = tid >> 6, lane = tid & 63;
    const int l15 = lane & 15, quad = lane >> 4;
    const int row0 = blockIdx.y * 128, col0 = blockIdx.x * 128;
    const int wr = (wave >> 1) * 64, wc = (wave & 1) * 64;
    const int sr = lane >> 2, kof = (lane & 3) * 8;

    f32x4 acc[4][4];
    #pragma unroll
    for (int i = 0; i < 4; i++)
        #pragma unroll
        for (int j = 0; j < 4; j++)
            acc[i][j] = (f32x4){0.f, 0.f, 0.f, 0.f};

#define GSTAGE(KT, BUF) do {                                                   \
        _Pragma("unroll")                                                      \
        for (int i_ = 0; i_ < 2; i_++) {                                       \
            const int rr = i_ * 64 + wave * 16;                                \
            gload_lds16(A + (size_t)(row0 + rr + sr) * K + (KT) + kof,         \
                        &As[BUF][rr * 32]);                                    \
            gload_lds16(Bt + (size_t)(col0 + rr + sr) * K + (KT) + kof,        \
                        &Bs[BUF][rr * 32]);                                    \
        }                                                                      \
    } while (0)

    GSTAGE(0, 0);
    GSTAGE(32, 1);
    asm volatile("s_waitcnt vmcnt(4)" ::: "memory");   // tile 0 landed
    __builtin_amdgcn_s_barrier();

    const int nkt = K >> 5;
    int cur = 0, nxt = 2;
    for (int t = 0; t < nkt; ++t) {
        if (t + 2 < nkt) GSTAGE((t + 2) * 32, nxt);

        bf16x8 af[4], bfr[4];
        #pragma unroll
        for (int mt = 0; mt < 4; mt++)
            af[mt] = *(const bf16x8*)&As[cur][(wr + mt * 16 + l15) * 32 + quad * 8];
        #pragma unroll
        for (int nt = 0; nt < 4; nt++)
            bfr[nt] = *(const bf16x8*)&Bs[cur][(wc + nt * 16 + l15) * 32 + quad * 8];
        #pragma unroll
        for (int mt = 0; mt < 4; mt++)
            #pragma unroll
            for (int nt = 0; nt < 4; nt++)
                acc[mt][nt] = __builtin_amdgcn_mfma_f32_16x16x32_bf16(
                    af[mt], bfr[nt], acc[mt][nt], 0, 0, 0);

        if (t + 2 < nkt)
            asm volatile("s_waitcnt vmcnt(4)" ::: "memory");  // t+1 landed
        else
            asm volatile("s_waitcnt vmcnt(0)" ::: "memory");  // tail drain
        __builtin_amdgcn_s_barrier();
        cur = (cur == 2) ? 0 : cur + 1;
        nxt = (nxt == 2) ? 0 : nxt + 1;
    }
#undef GSTAGE

    #pragma unroll
    for (int mt = 0; mt < 4; mt++) {
        #pragma unroll
        for (int r = 0; r < 4; r++) {
            const size_t row = row0 + wr + mt * 16 + quad * 4 + r;
            #pragma unroll
            for (int nt = 0; nt < 4; nt++) {
                const size_t col = col0 + wc + nt * 16 + l15;
                if (OUT_BF16)
                    ((short*)Cout)[row * N + col] = f2bf(acc[mt][nt][r]);
                else
                    ((float*)Cout)[row * N + col] = acc[mt][nt][r];
            }
        }
    }
}

// ---------------- K/V tiling prepass: MFMA fragment-stream layout ---------
// Per (bk, jt) 4096-short tile, chunk i (0..7) of 512 shorts, lane = quad*16+l15:
//  K-tile chunk i=nt*2+k0, lane, j :  K[nt*16 + l15][(k0*4+quad)*8 + j]
//  V-tile chunk i=nt*2+k0, lane, j :  V^T[nt*16 + l15][k0*32 + quad*8 + j]
// so attn's kf[i]/vf[i] = one coalesced 16B/lane global load, no LDS.
__global__ __launch_bounds__(256) void kv_tile(
    const short* __restrict__ QKV, short* __restrict__ Kt, short* __restrict__ Vt)
{
    __shared__ short Ls[64 * 72];
    const int jt = blockIdx.x;         // 0..31
    const int bk = blockIdx.y;         // 0..7 = b*4+kh
    const int b = bk >> 2, kh = bk & 3;
    const int tid = threadIdx.x;
    const int key = tid >> 2, d16 = (tid & 3) * 16;
    const size_t src = (size_t)(b * T_ + jt * 64 + key) * NQKV_ + C_ + kh * 64 + d16;
    const size_t tbase = (size_t)(bk * 32 + jt) * 4096;

    {   // K: thread holds K[key][d16..d16+15] -> stream position
        const int i = (key >> 4) * 2 + (d16 >> 5);
        const int qd = (d16 & 31) >> 3;           // quad of first 8: 0 or 2
        short* dst = Kt + tbase + i * 512 + (qd * 16 + (key & 15)) * 8;
        *(bf16x8*)dst         = *(const bf16x8*)(QKV + src);      // d16..+7
        *(bf16x8*)(dst + 128) = *(const bf16x8*)(QKV + src + 8);  // d16+8..+15
    }
    // V: transpose through LDS, then stream-store
    *(bf16x8*)&Ls[key * 72 + d16]     = *(const bf16x8*)(QKV + src + KVC_);
    *(bf16x8*)&Ls[key * 72 + d16 + 8] = *(const bf16x8*)(QKV + src + KVC_ + 8);
    __syncthreads();
    const int d = tid >> 2, k16 = (tid & 3) * 16;
    bf16x8 o0, o1;
    #pragma unroll
    for (int i = 0; i < 8; i++) o0[i] = Ls[(k16 + i) * 72 + d];      // V^T[d][k16..+7]
    #pragma unroll
    for (int i = 0; i < 8; i++) o1[i] = Ls[(k16 + 8 + i) * 72 + d];  // V^T[d][k16+8..+15]
    {
        const int i = (d >> 4) * 2 + (k16 >> 5);
        const int qk = (k16 & 31) >> 3;           // 0 or 2
        short* dst = Vt + tbase + i * 512 + (qk * 16 + (d & 15)) * 8;
        *(bf16x8*)dst         = o0;
        *(bf16x8*)(dst + 128) = o1;
    }
}

// ---------------- MFMA flash attention, pipelined dual-pipe ---------------
// round-8 version (measured best total): paired q-tiles, frag-stream K/V
// global->VGPR, no main-loop barriers, QK[j+1] between P-write[j] and
// P-read[j] (ping-pong s-state), s_setprio(1) around MFMA clusters.
#define LSTR 72

// one pipeline stage: softmax[j] from SCUR; QK[j+1] into SNXT; PV[j].
#define ATTN_ITER(J, SCURH, SCURL, SNXTH, SNXTL)                               \
  {                                                                            \
    const int j_ = (J);                                                        \
    const bool doL_ = (j_ <= qtL);                                             \
    /* softmax H from SCURH */                                                 \
    {                                                                          \
        const float base = slope2 * (float)(j_ * 64 + l15 - quad * 4 - qrow0H);\
        if (j_ == qtH) {                                                       \
            _Pragma("unroll")                                                  \
            for (int nt = 0; nt < 4; nt++) {                                   \
                const int colsw = ((nt * 16 + l15) ^ wswz);                    \
                _Pragma("unroll")                                              \
                for (int r = 0; r < 4; r++) {                                  \
                    const float relv = (float)(j_ * 64 + l15 - quad * 4 - qrow0H)\
                                     + (float)(nt * 16 - r);                   \
                    float p = __builtin_amdgcn_exp2f(                          \
                        fmaf(slope2, (float)(nt * 16 - r), base) + SCURH[nt][r]);\
                    if (relv > 0.f) p = 0.f;                                   \
                    Pw[(quad * 4 + r) * LSTR + colsw] = f2bf_trunc(p);         \
                }                                                              \
            }                                                                  \
        } else {                                                               \
            _Pragma("unroll")                                                  \
            for (int nt = 0; nt < 4; nt++) {                                   \
                const int colsw = ((nt * 16 + l15) ^ wswz);                    \
                _Pragma("unroll")                                              \
                for (int r = 0; r < 4; r++) {                                  \
                    float p = __builtin_amdgcn_exp2f(                          \
                        fmaf(slope2, (float)(nt * 16 - r), base) + SCURH[nt][r]);\
                    Pw[(quad * 4 + r) * LSTR + colsw] = f2bf_trunc(p);         \
                }                                                              \
            }                                                                  \
        }                                                                      \
    }                                                                          \
    if (doL_) {                                                                \
        const float base = slope2 * (float)(j_ * 64 + l15 - quad * 4 - qrow0L);\
        if (j_ == qtL) {                                                       \
            _Pragma("unroll")                                                  \
            for (int nt = 0; nt < 4; nt++) {                                   \
                const int colsw = ((nt * 16 + l15) ^ wswz);                    \
                _Pragma("unroll")                                              \
                for (int r = 0; r < 4; r++) {                                  \
                    const float relv = (float)(j_ * 64 + l15 - quad * 4 - qrow0L)\
                                     + (float)(nt * 16 - r);                   \
                    float p = __builtin_amdgcn_exp2f(                          \
                        fmaf(slope2, (float)(nt * 16 - r), base) + SCURL[nt][r]);\
                    if (relv > 0.f) p = 0.f;                                   \
                    Pw[(16 + quad * 4 + r) * LSTR + colsw] = f2bf_trunc(p);    \
                }                                                              \
            }                                                                  \
        } else {                                                               \
            _Pragma("unroll")                                                  \
            for (int nt = 0; nt < 4; nt++) {                                   \
                const int colsw = ((nt * 16 + l15) ^ wswz);                    \
                _Pragma("unroll")                                              \
                for (int r = 0; r < 4; r++) {                                  \
                    float p = __builtin_amdgcn_exp2f(                          \
                        fmaf(slope2, (float)(nt * 16 - r), base) + SCURL[nt][r]);\
                    Pw[(16 + quad * 4 + r) * LSTR + colsw] = f2bf_trunc(p);    \
                }                                                              \
            }                                                                  \
        }                                                                      \
    }                                                                          \
    /* QK[j+1] (register-only) fills the LDS write->read gap */                \
    if (j_ < qtH) {                                                            \
        const bool doLn_ = (j_ + 1 <= qtL);                                    \
        __builtin_amdgcn_s_setprio(1);                                         \
        _Pragma("unroll")                                                      \
        for (int nt = 0; nt < 4; nt++) {                                       \
            f32x4 a = {0.f, 0.f, 0.f, 0.f};                                    \
            a = __builtin_amdgcn_mfma_f32_16x16x32_bf16(qfH[0], kf[nt*2+0], a, 0, 0, 0);\
            a = __builtin_amdgcn_mfma_f32_16x16x32_bf16(qfH[1], kf[nt*2+1], a, 0, 0, 0);\
            SNXTH[nt] = a;                                                     \
        }                                                                      \
        if (doLn_) {                                                           \
            _Pragma("unroll")                                                  \
            for (int nt = 0; nt < 4; nt++) {                                   \
                f32x4 a = {0.f, 0.f, 0.f, 0.f};                                \
                a = __builtin_amdgcn_mfma_f32_16x16x32_bf16(qfL[0], kf[nt*2+0], a, 0, 0, 0);\
                a = __builtin_amdgcn_mfma_f32_16x16x32_bf16(qfL[1], kf[nt*2+1], a, 0, 0, 0);\
                SNXTL[nt] = a;                                                 \
            }                                                                  \
        }                                                                      \
        __builtin_amdgcn_s_setprio(0);                                         \
        const int pk_ = (j_ + 2 <= qtH) ? j_ + 2 : qtH;                        \
        _Pragma("unroll")                                                      \
        for (int i = 0; i < 8; i++)                                            \
            kf[i] = *(const bf16x8*)(Kt + (size_t)pk_ * 4096 + i * 512 + lane * 8);\
    }                                                                          \
    __asm__ volatile("s_waitcnt lgkmcnt(0)" ::: "memory");                     \
    /* PV[j]: O += P @ V, l += P @ 1 */                                        \
    {                                                                          \
        bf16x8 pf0 = *(const bf16x8*)&Pw[l15 * LSTR + ((quad * 8) ^ rswz)];    \
        bf16x8 pf1 = *(const bf16x8*)&Pw[l15 * LSTR + ((32 + quad * 8) ^ rswz)];\
        __builtin_amdgcn_s_setprio(1);                                         \
        laccH = __builtin_amdgcn_mfma_f32_16x16x32_bf16(pf0, ones, laccH, 0, 0, 0);\
        laccH = __builtin_amdgcn_mfma_f32_16x16x32_bf16(pf1, ones, laccH, 0, 0, 0);\
        _Pragma("unroll")                                                      \
        for (int nt = 0; nt < 4; nt++) {                                       \
            OaccH[nt] = __builtin_amdgcn_mfma_f32_16x16x32_bf16(               \
                pf0, vf[nt*2+0], OaccH[nt], 0, 0, 0);                          \
            OaccH[nt] = __builtin_amdgcn_mfma_f32_16x16x32_bf16(               \
                pf1, vf[nt*2+1], OaccH[nt], 0, 0, 0);                          \
        }                                                                      \
        __builtin_amdgcn_s_setprio(0);                                         \
    }                                                                          \
    if (doL_) {                                                                \
        bf16x8 pf0 = *(const bf16x8*)&Pw[(16 + l15) * LSTR + ((quad * 8) ^ rswz)];\
        bf16x8 pf1 = *(const bf16x8*)&Pw[(16 + l15) * LSTR + ((32 + quad * 8) ^ rswz)];\
        __builtin_amdgcn_s_setprio(1);                                         \
        laccL = __builtin_amdgcn_mfma_f32_16x16x32_bf16(pf0, ones, laccL, 0, 0, 0);\
        laccL = __builtin_amdgcn_mfma_f32_16x16x32_bf16(pf1, ones, laccL, 0, 0, 0);\
        _Pragma("unroll")                                                      \
        for (int nt = 0; nt < 4; nt++) {                                       \
            OaccL[nt] = __builtin_amdgcn_mfma_f32_16x16x32_bf16(               \
                pf0, vf[nt*2+0], OaccL[nt], 0, 0, 0);                          \
            OaccL[nt] = __builtin_amdgcn_mfma_f32_16x16x32_bf16(               \
                pf1, vf[nt*2+1], OaccL[nt], 0, 0, 0);                          \
        }                                                                      \
        __builtin_amdgcn_s_setprio(0);                                         \
    }                                                                          \
    const int pv_ = (j_ + 1 <= qtH) ? j_ + 1 : qtH;                            \
    _Pragma("unroll")                                                          \
    for (int i = 0; i < 8; i++)                                                \
        vf[i] = *(const bf16x8*)(Vt + (size_t)pv_ * 4096 + i * 512 + lane * 8);\
  }

__global__ __launch_bounds__(256, 2) void attn_mfma(
    const short* __restrict__ QKV, const short* __restrict__ Ktg,
    const short* __restrict__ Vtg, short* __restrict__ Y)
{
    const int qx = blockIdx.x;                 // 0..15
    const int bh = blockIdx.y;
    const int qtL = qx, qtH = NQT_ - 1 - qx;   // pair sums to 31
    const int b = bh >> 4, h = bh & 15, kh = h >> 2;
    const float slope2 = exp2f(-0.5f * (float)(kh + 1)) * 1.44269504f;
    const int tid = threadIdx.x;
    const int wave = tid >> 6, lane = tid & 63;
    const int l15 = lane & 15, quad = lane >> 4;

    __shared__ short Ps[4 * 32 * LSTR];        // per wave: rows 0-15 H, 16-31 L
    short* Pw = &Ps[wave * 32 * LSTR];
    const int wswz = ((quad >> 1) & 1) << 4;   // P write XOR (row bit3)
    const int rswz = ((l15 >> 3) & 1) << 4;    // P read  XOR (row bit3)

    const size_t bT = (size_t)b * T_;
    const size_t tb0 = (size_t)((b * HKV_ + kh) * 32) * 4096;
    const short* Kt = Ktg + tb0;
    const short* Vt = Vtg + tb0;
    const int qrow0H = qtH * 64 + wave * 16;
    const int qrow0L = qtL * 64 + wave * 16;

    // Q fragments; scale 1/8 * 1/ln2 folded in (exp2-domain scores)
    const float qscale = 0.125f * 1.44269504f;
    bf16x8 qfH[2], qfL[2];
    #pragma unroll
    for (int k0 = 0; k0 < 2; k0++) {
        const short* qpH = QKV + (bT + qrow0H + l15) * NQKV_ + h * 64;
        const short* qpL = QKV + (bT + qrow0L + l15) * NQKV_ + h * 64;
        bf16x8 rH = *(const bf16x8*)(qpH + k0 * 32 + quad * 8);
        bf16x8 rL = *(const bf16x8*)(qpL + k0 * 32 + quad * 8);
        #pragma unroll
        for (int j = 0; j < 8; j++) {
            qfH[k0][j] = f2bf(bf2f(rH[j]) * qscale);
            qfL[k0][j] = f2bf(bf2f(rL[j]) * qscale);
        }
    }

    const short one_s = (short)0x3F80;         // bf16 1.0
    const bf16x8 ones = {one_s, one_s, one_s, one_s, one_s, one_s, one_s, one_s};

    f32x4 OaccH[4], OaccL[4], laccH, laccL;
    #pragma unroll
    for (int nt = 0; nt < 4; nt++) {
        OaccH[nt] = (f32x4){0.f, 0.f, 0.f, 0.f};
        OaccL[nt] = (f32x4){0.f, 0.f, 0.f, 0.f};
    }
    laccH = (f32x4){0.f, 0.f, 0.f, 0.f};
    laccL = (f32x4){0.f, 0.f, 0.f, 0.f};

    // prologue: K/V tile-0 fragments, then QK[0] into the A s-state
    bf16x8 kf[8], vf[8];
    #pragma unroll
    for (int i = 0; i < 8; i++)
        kf[i] = *(const bf16x8*)(Kt + i * 512 + lane * 8);
    #pragma unroll
    for (int i = 0; i < 8; i++)
        vf[i] = *(const bf16x8*)(Vt + i * 512 + lane * 8);

    f32x4 sAH[4], sAL[4], sBH[4], sBL[4];
    #pragma unroll
    for (int nt = 0; nt < 4; nt++) {
        f32x4 a = {0.f, 0.f, 0.f, 0.f};
        a = __builtin_amdgcn_mfma_f32_16x16x32_bf16(qfH[0], kf[nt*2+0], a, 0, 0, 0);
        a = __builtin_amdgcn_mfma_f32_16x16x32_bf16(qfH[1], kf[nt*2+1], a, 0, 0, 0);
        sAH[nt] = a;
    }
    #pragma unroll
    for (int nt = 0; nt < 4; nt++) {           // doL(0) is always true
        f32x4 a = {0.f, 0.f, 0.f, 0.f};
        a = __builtin_amdgcn_mfma_f32_16x16x32_bf16(qfL[0], kf[nt*2+0], a, 0, 0, 0);
        a = __builtin_amdgcn_mfma_f32_16x16x32_bf16(qfL[1], kf[nt*2+1], a, 0, 0, 0);
        sAL[nt] = a;
    }
    {   // prefetch K tile 1 (qtH >= 16, so tile 1 always exists)
        #pragma unroll
        for (int i = 0; i < 8; i++)
            kf[i] = *(const bf16x8*)(Kt + (size_t)4096 + i * 512 + lane * 8);
    }

    for (int j = 0; j <= qtH; j += 2) {
        ATTN_ITER(j, sAH, sAL, sBH, sBL);
        if (j + 1 <= qtH)
            ATTN_ITER(j + 1, sBH, sBL, sAH, sAL);
    }

    // epilogue: l = lacc[r] (same in all 16 col-lanes), normalize, store bf16
    #pragma unroll
    for (int r = 0; r < 4; r++) {
        const float invH = 1.f / laccH[r];
        const float invL = 1.f / laccL[r];
        const int rowH = qrow0H + quad * 4 + r;
        const int rowL = qrow0L + quad * 4 + r;
        short* ypH = Y + (bT + rowH) * C_ + h * 64 + l15;
        short* ypL = Y + (bT + rowL) * C_ + h * 64 + l15;
        #pragma unroll
        for (int nt = 0; nt < 4; nt++) {
            ypH[nt * 16] = f2bf(OaccH[nt][r] * invH);
            ypL[nt * 16] = f2bf(OaccL[nt][r] * invL);
        }
    }
}

extern "C" void kernel_launch(void* const* d_in, const int* in_sizes, int n_in,
                              void* d_out, int out_size, void* d_ws, size_t ws_size,
                              hipStream_t stream) {
    const float* x  = (const float*)d_in[0];
    const float* Wq = (const float*)d_in[1];
    const float* Wk = (const float*)d_in[2];
    const float* Wv = (const float*)d_in[3];
    const float* Wo = (const float*)d_in[4];
    float* out = (float*)d_out;

    const int M = B_ * T_;                           // 4096
    short* xb  = (short*)d_ws;                       // [4096][1024]
    short* Wt  = xb  + (size_t)M * C_;               // [1536][1024]
    short* Wot = Wt  + (size_t)NQKV_ * C_;           // [1024][1024]
    short* QKV = Wot + (size_t)C_ * C_;              // [4096][1536]
    short* Yb  = QKV + (size_t)M * NQKV_;            // [4096][1024]
    short* Ktg = Yb  + (size_t)M * C_;               // [8][32][4096] frag-stream
    short* Vtg = Ktg + (size_t)8 * 32 * 4096;        // [8][32][4096] frag-stream

    cast_bf16<<<dim3(M * C_ / (256 * 8)), dim3(256), 0, stream>>>(x, xb, M * C_);
    w_transpose<<<dim3(32, 32, 4), dim3(32, 8), 0, stream>>>(Wq, Wk, Wv, Wo, Wt, Wot);

    gemm_bf16<true><<<dim3(NQKV_ / 128, M / 128), dim3(256), 0, stream>>>(
        xb, Wt, QKV, M, NQKV_, C_);
    kv_tile<<<dim3(32, 8), dim3(256), 0, stream>>>(QKV, Ktg, Vtg);
    attn_mfma<<<dim3(NQT_ / 2, B_ * H_), dim3(256), 0, stream>>>(QKV, Ktg, Vtg, Yb);
    gemm_bf16<false><<<dim3(C_ / 128, M / 128), dim3(256), 0, stream>>>(
        Yb, Wot, out, M, C_, C_);
}

// Round 12
// 164.537 us; speedup vs baseline: 1.0599x; 1.0599x over previous
//
#include <hip/hip_runtime.h>
#include <hip/hip_bf16.h>
#include <math.h>

#define B_ 2
#define T_ 2048
#define C_ 1024
#define H_ 16
#define HKV_ 4
#define G_ 4
#define HD_ 64
#define KVC_ 256      // HKV*HD
#define NQKV_ 1536    // C_ + 2*KVC_
#define NQT_ 32       // T_/64 q-tiles

typedef __attribute__((ext_vector_type(8))) short bf16x8;
typedef __attribute__((ext_vector_type(4))) float f32x4;

static __device__ inline short f2bf(float f) {          // RNE (off hot path)
    __hip_bfloat16 h = __float2bfloat16(f);
    short s;
    __builtin_memcpy(&s, &h, 2);
    return s;
}
static __device__ inline short f2bf_trunc(float f) {    // RTZ, 1 op (hot path)
    unsigned int u;
    __builtin_memcpy(&u, &f, 4);
    return (short)(u >> 16);
}
static __device__ inline float bf2f(short s) {
    unsigned int u = ((unsigned int)(unsigned short)s) << 16;
    float f;
    __builtin_memcpy(&f, &u, 4);
    return f;
}

// async global->LDS, 16B per lane; lds base wave-uniform, dest = base + lane*16.
static __device__ inline void gload_lds16(const short* g, short* lds) {
    __builtin_amdgcn_global_load_lds(
        (const __attribute__((address_space(1))) unsigned int*)g,
        (__attribute__((address_space(3))) unsigned int*)lds, 16, 0, 0);
}

// ---------------- elementwise fp32 -> bf16 cast (8 elems/thread) ----------
__global__ __launch_bounds__(256) void cast_bf16(
    const float* __restrict__ in, short* __restrict__ out, int n)
{
    const int i = (blockIdx.x * 256 + threadIdx.x) * 8;
    if (i >= n) return;
    const float4 a = *(const float4*)(in + i);
    const float4 b = *(const float4*)(in + i + 4);
    bf16x8 o;
    o[0] = f2bf(a.x); o[1] = f2bf(a.y); o[2] = f2bf(a.z); o[3] = f2bf(a.w);
    o[4] = f2bf(b.x); o[5] = f2bf(b.y); o[6] = f2bf(b.z); o[7] = f2bf(b.w);
    *(bf16x8*)(out + i) = o;
}

// ------------- fused weight transpose+cast (z selects matrix) -------------
__global__ __launch_bounds__(256) void w_transpose(
    const float* __restrict__ Wq, const float* __restrict__ Wk,
    const float* __restrict__ Wv, const float* __restrict__ Wo,
    short* __restrict__ Wt, short* __restrict__ Wot)
{
    const int z = blockIdx.z;
    const float* in;
    short* out;
    int N;
    if (z == 0)      { in = Wq; out = Wt;                     N = C_; }
    else if (z == 1) { in = Wk; out = Wt + C_ * C_;           N = KVC_; }
    else if (z == 2) { in = Wv; out = Wt + (C_ + KVC_) * C_;  N = KVC_; }
    else             { in = Wo; out = Wot;                    N = C_; }
    const int n0 = blockIdx.x * 32;
    if (n0 >= N) return;
    __shared__ float t[32][33];
    const int tx = threadIdx.x, ty = threadIdx.y;     // 32 x 8
    const int k0 = blockIdx.y * 32;
    #pragma unroll
    for (int j = 0; j < 4; j++)
        t[ty + j * 8][tx] = in[(size_t)(k0 + ty + j * 8) * N + n0 + tx];
    __syncthreads();
    #pragma unroll
    for (int j = 0; j < 4; j++)
        out[(size_t)(n0 + ty + j * 8) * C_ + k0 + tx] = f2bf(t[tx][ty + j * 8]);
}

// ------ bf16 MFMA GEMM: 64x128 tile, BK=32, 3-buffer 2-deep prefetch ------
// TLP-first geometry: 64x128 tile doubles the grid vs 128x128 (gemm1: 768
// blocks = 3/CU, gemm2: 512 = 2/CU) so inter-block overlap covers the load
// latency the in-block pipeline can't. Counted vmcnt(3) (3 loads/wave/stage,
// never 0 mid-loop): stage t+2 while computing t, wait only for t+1.
// Bijective XCD swizzle (grids are %8==0): each XCD owns a contiguous block
// range -> its full B panel (<=3MB) + ~8 A-panels fit the 4MB per-XCD L2.
template <bool OUT_BF16>
__global__ __launch_bounds__(256) void gemm_bf16(
    const short* __restrict__ A, const short* __restrict__ Bt,
    void* __restrict__ Cout, int M, int N, int K)
{
    __shared__ short As[3][64 * 32];
    __shared__ short Bs[3][128 * 32];
    const int tid = threadIdx.x;
    const int wave = tid >> 6, lane = tid & 63;
    const int l15 = lane & 15, quad = lane >> 4;

    // XCD-aware bijective swizzle (requires nwg % 8 == 0; both grids comply)
    const int gx = gridDim.x;
    const int nwg = gx * gridDim.y;
    int bid = blockIdx.y * gx + blockIdx.x;
    bid = (bid & 7) * (nwg >> 3) + (bid >> 3);
    const int row0 = (bid / gx) * 64, col0 = (bid % gx) * 128;

    const int wr = (wave >> 1) * 32, wc = (wave & 1) * 64;
    const int sr = lane >> 2, kof = (lane & 3) * 8;

    f32x4 acc[2][4];
    #pragma unroll
    for (int i = 0; i < 2; i++)
        #pragma unroll
        for (int j = 0; j < 4; j++)
            acc[i][j] = (f32x4){0.f, 0.f, 0.f, 0.f};

#define GSTAGE(KT, BUF) do {                                                   \
        gload_lds16(A + (size_t)(row0 + wave * 16 + sr) * K + (KT) + kof,      \
                    &As[BUF][wave * 512]);                                     \
        gload_lds16(Bt + (size_t)(col0 + (wave * 2) * 16 + sr) * K + (KT) + kof,\
                    &Bs[BUF][(wave * 2) * 512]);                               \
        gload_lds16(Bt + (size_t)(col0 + (wave * 2 + 1) * 16 + sr) * K + (KT) + kof,\
                    &Bs[BUF][(wave * 2 + 1) * 512]);                           \
    } while (0)

    GSTAGE(0, 0);
    GSTAGE(32, 1);
    asm volatile("s_waitcnt vmcnt(3)" ::: "memory");   // tile 0 landed
    __builtin_amdgcn_s_barrier();

    const int nkt = K >> 5;
    int cur = 0, nxt = 2;
    for (int t = 0; t < nkt; ++t) {
        if (t + 2 < nkt) GSTAGE((t + 2) * 32, nxt);

        bf16x8 af[2], bfr[4];
        #pragma unroll
        for (int mt = 0; mt < 2; mt++)
            af[mt] = *(const bf16x8*)&As[cur][(wr + mt * 16 + l15) * 32 + quad * 8];
        #pragma unroll
        for (int nt = 0; nt < 4; nt++)
            bfr[nt] = *(const bf16x8*)&Bs[cur][(wc + nt * 16 + l15) * 32 + quad * 8];
        #pragma unroll
        for (int mt = 0; mt < 2; mt++)
            #pragma unroll
            for (int nt = 0; nt < 4; nt++)
                acc[mt][nt] = __builtin_amdgcn_mfma_f32_16x16x32_bf16(
                    af[mt], bfr[nt], acc[mt][nt], 0, 0, 0);

        if (t + 2 < nkt)
            asm volatile("s_waitcnt vmcnt(3)" ::: "memory");  // t+1 landed
        else
            asm volatile("s_waitcnt vmcnt(0)" ::: "memory");  // tail drain
        __builtin_amdgcn_s_barrier();
        cur = (cur == 2) ? 0 : cur + 1;
        nxt = (nxt == 2) ? 0 : nxt + 1;
    }
#undef GSTAGE

    #pragma unroll
    for (int mt = 0; mt < 2; mt++) {
        #pragma unroll
        for (int r = 0; r < 4; r++) {
            const size_t row = row0 + wr + mt * 16 + quad * 4 + r;
            #pragma unroll
            for (int nt = 0; nt < 4; nt++) {
                const size_t col = col0 + wc + nt * 16 + l15;
                if (OUT_BF16)
                    ((short*)Cout)[row * N + col] = f2bf(acc[mt][nt][r]);
                else
                    ((float*)Cout)[row * N + col] = acc[mt][nt][r];
            }
        }
    }
}

// ---------------- K/V tiling prepass: MFMA fragment-stream layout ---------
// Per (bk, jt) 4096-short tile, chunk i (0..7) of 512 shorts, lane = quad*16+l15:
//  K-tile chunk i=nt*2+k0, lane, j :  K[nt*16 + l15][(k0*4+quad)*8 + j]
//  V-tile chunk i=nt*2+k0, lane, j :  V^T[nt*16 + l15][k0*32 + quad*8 + j]
// so attn's kf[i]/vf[i] = one coalesced 16B/lane global load, no LDS.
__global__ __launch_bounds__(256) void kv_tile(
    const short* __restrict__ QKV, short* __restrict__ Kt, short* __restrict__ Vt)
{
    __shared__ short Ls[64 * 72];
    const int jt = blockIdx.x;         // 0..31
    const int bk = blockIdx.y;         // 0..7 = b*4+kh
    const int b = bk >> 2, kh = bk & 3;
    const int tid = threadIdx.x;
    const int key = tid >> 2, d16 = (tid & 3) * 16;
    const size_t src = (size_t)(b * T_ + jt * 64 + key) * NQKV_ + C_ + kh * 64 + d16;
    const size_t tbase = (size_t)(bk * 32 + jt) * 4096;

    {   // K: thread holds K[key][d16..d16+15] -> stream position
        const int i = (key >> 4) * 2 + (d16 >> 5);
        const int qd = (d16 & 31) >> 3;           // quad of first 8: 0 or 2
        short* dst = Kt + tbase + i * 512 + (qd * 16 + (key & 15)) * 8;
        *(bf16x8*)dst         = *(const bf16x8*)(QKV + src);      // d16..+7
        *(bf16x8*)(dst + 128) = *(const bf16x8*)(QKV + src + 8);  // d16+8..+15
    }
    // V: transpose through LDS, then stream-store
    *(bf16x8*)&Ls[key * 72 + d16]     = *(const bf16x8*)(QKV + src + KVC_);
    *(bf16x8*)&Ls[key * 72 + d16 + 8] = *(const bf16x8*)(QKV + src + KVC_ + 8);
    __syncthreads();
    const int d = tid >> 2, k16 = (tid & 3) * 16;
    bf16x8 o0, o1;
    #pragma unroll
    for (int i = 0; i < 8; i++) o0[i] = Ls[(k16 + i) * 72 + d];      // V^T[d][k16..+7]
    #pragma unroll
    for (int i = 0; i < 8; i++) o1[i] = Ls[(k16 + 8 + i) * 72 + d];  // V^T[d][k16+8..+15]
    {
        const int i = (d >> 4) * 2 + (k16 >> 5);
        const int qk = (k16 & 31) >> 3;           // 0 or 2
        short* dst = Vt + tbase + i * 512 + (qk * 16 + (d & 15)) * 8;
        *(bf16x8*)dst         = o0;
        *(bf16x8*)(dst + 128) = o1;
    }
}

// ---------------- MFMA flash attention, pipelined dual-pipe ---------------
// round-8 version (measured best total): paired q-tiles, frag-stream K/V
// global->VGPR, no main-loop barriers, QK[j+1] between P-write[j] and
// P-read[j] (ping-pong s-state), s_setprio(1) around MFMA clusters.
#define LSTR 72

// one pipeline stage: softmax[j] from SCUR; QK[j+1] into SNXT; PV[j].
#define ATTN_ITER(J, SCURH, SCURL, SNXTH, SNXTL)                               \
  {                                                                            \
    const int j_ = (J);                                                        \
    const bool doL_ = (j_ <= qtL);                                             \
    /* softmax H from SCURH */                                                 \
    {                                                                          \
        const float base = slope2 * (float)(j_ * 64 + l15 - quad * 4 - qrow0H);\
        if (j_ == qtH) {                                                       \
            _Pragma("unroll")                                                  \
            for (int nt = 0; nt < 4; nt++) {                                   \
                const int colsw = ((nt * 16 + l15) ^ wswz);                    \
                _Pragma("unroll")                                              \
                for (int r = 0; r < 4; r++) {                                  \
                    const float relv = (float)(j_ * 64 + l15 - quad * 4 - qrow0H)\
                                     + (float)(nt * 16 - r);                   \
                    float p = __builtin_amdgcn_exp2f(                          \
                        fmaf(slope2, (float)(nt * 16 - r), base) + SCURH[nt][r]);\
                    if (relv > 0.f) p = 0.f;                                   \
                    Pw[(quad * 4 + r) * LSTR + colsw] = f2bf_trunc(p);         \
                }                                                              \
            }                                                                  \
        } else {                                                               \
            _Pragma("unroll")                                                  \
            for (int nt = 0; nt < 4; nt++) {                                   \
                const int colsw = ((nt * 16 + l15) ^ wswz);                    \
                _Pragma("unroll")                                              \
                for (int r = 0; r < 4; r++) {                                  \
                    float p = __builtin_amdgcn_exp2f(                          \
                        fmaf(slope2, (float)(nt * 16 - r), base) + SCURH[nt][r]);\
                    Pw[(quad * 4 + r) * LSTR + colsw] = f2bf_trunc(p);         \
                }                                                              \
            }                                                                  \
        }                                                                      \
    }                                                                          \
    if (doL_) {                                                                \
        const float base = slope2 * (float)(j_ * 64 + l15 - quad * 4 - qrow0L);\
        if (j_ == qtL) {                                                       \
            _Pragma("unroll")                                                  \
            for (int nt = 0; nt < 4; nt++) {                                   \
                const int colsw = ((nt * 16 + l15) ^ wswz);                    \
                _Pragma("unroll")                                              \
                for (int r = 0; r < 4; r++) {                                  \
                    const float relv = (float)(j_ * 64 + l15 - quad * 4 - qrow0L)\
                                     + (float)(nt * 16 - r);                   \
                    float p = __builtin_amdgcn_exp2f(                          \
                        fmaf(slope2, (float)(nt * 16 - r), base) + SCURL[nt][r]);\
                    if (relv > 0.f) p = 0.f;                                   \
                    Pw[(16 + quad * 4 + r) * LSTR + colsw] = f2bf_trunc(p);    \
                }                                                              \
            }                                                                  \
        } else {                                                               \
            _Pragma("unroll")                                                  \
            for (int nt = 0; nt < 4; nt++) {                                   \
                const int colsw = ((nt * 16 + l15) ^ wswz);                    \
                _Pragma("unroll")                                              \
                for (int r = 0; r < 4; r++) {                                  \
                    float p = __builtin_amdgcn_exp2f(                          \
                        fmaf(slope2, (float)(nt * 16 - r), base) + SCURL[nt][r]);\
                    Pw[(16 + quad * 4 + r) * LSTR + colsw] = f2bf_trunc(p);    \
                }                                                              \
            }                                                                  \
        }                                                                      \
    }                                                                          \
    /* QK[j+1] (register-only) fills the LDS write->read gap */                \
    if (j_ < qtH) {                                                            \
        const bool doLn_ = (j_ + 1 <= qtL);                                    \
        __builtin_amdgcn_s_setprio(1);                                         \
        _Pragma("unroll")                                                      \
        for (int nt = 0; nt < 4; nt++) {                                       \
            f32x4 a = {0.f, 0.f, 0.f, 0.f};                                    \
            a = __builtin_amdgcn_mfma_f32_16x16x32_bf16(qfH[0], kf[nt*2+0], a, 0, 0, 0);\
            a = __builtin_amdgcn_mfma_f32_16x16x32_bf16(qfH[1], kf[nt*2+1], a, 0, 0, 0);\
            SNXTH[nt] = a;                                                     \
        }                                                                      \
        if (doLn_) {                                                           \
            _Pragma("unroll")                                                  \
            for (int nt = 0; nt < 4; nt++) {                                   \
                f32x4 a = {0.f, 0.f, 0.f, 0.f};                                \
                a = __builtin_amdgcn_mfma_f32_16x16x32_bf16(qfL[0], kf[nt*2+0], a, 0, 0, 0);\
                a = __builtin_amdgcn_mfma_f32_16x16x32_bf16(qfL[1], kf[nt*2+1], a, 0, 0, 0);\
                SNXTL[nt] = a;                                                 \
            }                                                                  \
        }                                                                      \
        __builtin_amdgcn_s_setprio(0);                                         \
        const int pk_ = (j_ + 2 <= qtH) ? j_ + 2 : qtH;                        \
        _Pragma("unroll")                                                      \
        for (int i = 0; i < 8; i++)                                            \
            kf[i] = *(const bf16x8*)(Kt + (size_t)pk_ * 4096 + i * 512 + lane * 8);\
    }                                                                          \
    __asm__ volatile("s_waitcnt lgkmcnt(0)" ::: "memory");                     \
    /* PV[j]: O += P @ V, l += P @ 1 */                                        \
    {                                                                          \
        bf16x8 pf0 = *(const bf16x8*)&Pw[l15 * LSTR + ((quad * 8) ^ rswz)];    \
        bf16x8 pf1 = *(const bf16x8*)&Pw[l15 * LSTR + ((32 + quad * 8) ^ rswz)];\
        __builtin_amdgcn_s_setprio(1);                                         \
        laccH = __builtin_amdgcn_mfma_f32_16x16x32_bf16(pf0, ones, laccH, 0, 0, 0);\
        laccH = __builtin_amdgcn_mfma_f32_16x16x32_bf16(pf1, ones, laccH, 0, 0, 0);\
        _Pragma("unroll")                                                      \
        for (int nt = 0; nt < 4; nt++) {                                       \
            OaccH[nt] = __builtin_amdgcn_mfma_f32_16x16x32_bf16(               \
                pf0, vf[nt*2+0], OaccH[nt], 0, 0, 0);                          \
            OaccH[nt] = __builtin_amdgcn_mfma_f32_16x16x32_bf16(               \
                pf1, vf[nt*2+1], OaccH[nt], 0, 0, 0);                          \
        }                                                                      \
        __builtin_amdgcn_s_setprio(0);                                         \
    }                                                                          \
    if (doL_) {                                                                \
        bf16x8 pf0 = *(const bf16x8*)&Pw[(16 + l15) * LSTR + ((quad * 8) ^ rswz)];\
        bf16x8 pf1 = *(const bf16x8*)&Pw[(16 + l15) * LSTR + ((32 + quad * 8) ^ rswz)];\
        __builtin_amdgcn_s_setprio(1);                                         \
        laccL = __builtin_amdgcn_mfma_f32_16x16x32_bf16(pf0, ones, laccL, 0, 0, 0);\
        laccL = __builtin_amdgcn_mfma_f32_16x16x32_bf16(pf1, ones, laccL, 0, 0, 0);\
        _Pragma("unroll")                                                      \
        for (int nt = 0; nt < 4; nt++) {                                       \
            OaccL[nt] = __builtin_amdgcn_mfma_f32_16x16x32_bf16(               \
                pf0, vf[nt*2+0], OaccL[nt], 0, 0, 0);                          \
            OaccL[nt] = __builtin_amdgcn_mfma_f32_16x16x32_bf16(               \
                pf1, vf[nt*2+1], OaccL[nt], 0, 0, 0);                          \
        }                                                                      \
        __builtin_amdgcn_s_setprio(0);                                         \
    }                                                                          \
    const int pv_ = (j_ + 1 <= qtH) ? j_ + 1 : qtH;                            \
    _Pragma("unroll")                                                          \
    for (int i = 0; i < 8; i++)                                                \
        vf[i] = *(const bf16x8*)(Vt + (size_t)pv_ * 4096 + i * 512 + lane * 8);\
  }

__global__ __launch_bounds__(256, 2) void attn_mfma(
    const short* __restrict__ QKV, const short* __restrict__ Ktg,
    const short* __restrict__ Vtg, short* __restrict__ Y)
{
    const int qx = blockIdx.x;                 // 0..15
    const int bh = blockIdx.y;
    const int qtL = qx, qtH = NQT_ - 1 - qx;   // pair sums to 31
    const int b = bh >> 4, h = bh & 15, kh = h >> 2;
    const float slope2 = exp2f(-0.5f * (float)(kh + 1)) * 1.44269504f;
    const int tid = threadIdx.x;
    const int wave = tid >> 6, lane = tid & 63;
    const int l15 = lane & 15, quad = lane >> 4;

    __shared__ short Ps[4 * 32 * LSTR];        // per wave: rows 0-15 H, 16-31 L
    short* Pw = &Ps[wave * 32 * LSTR];
    const int wswz = ((quad >> 1) & 1) << 4;   // P write XOR (row bit3)
    const int rswz = ((l15 >> 3) & 1) << 4;    // P read  XOR (row bit3)

    const size_t bT = (size_t)b * T_;
    const size_t tb0 = (size_t)((b * HKV_ + kh) * 32) * 4096;
    const short* Kt = Ktg + tb0;
    const short* Vt = Vtg + tb0;
    const int qrow0H = qtH * 64 + wave * 16;
    const int qrow0L = qtL * 64 + wave * 16;

    // Q fragments; scale 1/8 * 1/ln2 folded in (exp2-domain scores)
    const float qscale = 0.125f * 1.44269504f;
    bf16x8 qfH[2], qfL[2];
    #pragma unroll
    for (int k0 = 0; k0 < 2; k0++) {
        const short* qpH = QKV + (bT + qrow0H + l15) * NQKV_ + h * 64;
        const short* qpL = QKV + (bT + qrow0L + l15) * NQKV_ + h * 64;
        bf16x8 rH = *(const bf16x8*)(qpH + k0 * 32 + quad * 8);
        bf16x8 rL = *(const bf16x8*)(qpL + k0 * 32 + quad * 8);
        #pragma unroll
        for (int j = 0; j < 8; j++) {
            qfH[k0][j] = f2bf(bf2f(rH[j]) * qscale);
            qfL[k0][j] = f2bf(bf2f(rL[j]) * qscale);
        }
    }

    const short one_s = (short)0x3F80;         // bf16 1.0
    const bf16x8 ones = {one_s, one_s, one_s, one_s, one_s, one_s, one_s, one_s};

    f32x4 OaccH[4], OaccL[4], laccH, laccL;
    #pragma unroll
    for (int nt = 0; nt < 4; nt++) {
        OaccH[nt] = (f32x4){0.f, 0.f, 0.f, 0.f};
        OaccL[nt] = (f32x4){0.f, 0.f, 0.f, 0.f};
    }
    laccH = (f32x4){0.f, 0.f, 0.f, 0.f};
    laccL = (f32x4){0.f, 0.f, 0.f, 0.f};

    // prologue: K/V tile-0 fragments, then QK[0] into the A s-state
    bf16x8 kf[8], vf[8];
    #pragma unroll
    for (int i = 0; i < 8; i++)
        kf[i] = *(const bf16x8*)(Kt + i * 512 + lane * 8);
    #pragma unroll
    for (int i = 0; i < 8; i++)
        vf[i] = *(const bf16x8*)(Vt + i * 512 + lane * 8);

    f32x4 sAH[4], sAL[4], sBH[4], sBL[4];
    #pragma unroll
    for (int nt = 0; nt < 4; nt++) {
        f32x4 a = {0.f, 0.f, 0.f, 0.f};
        a = __builtin_amdgcn_mfma_f32_16x16x32_bf16(qfH[0], kf[nt*2+0], a, 0, 0, 0);
        a = __builtin_amdgcn_mfma_f32_16x16x32_bf16(qfH[1], kf[nt*2+1], a, 0, 0, 0);
        sAH[nt] = a;
    }
    #pragma unroll
    for (int nt = 0; nt < 4; nt++) {           // doL(0) is always true
        f32x4 a = {0.f, 0.f, 0.f, 0.f};
        a = __builtin_amdgcn_mfma_f32_16x16x32_bf16(qfL[0], kf[nt*2+0], a, 0, 0, 0);
        a = __builtin_amdgcn_mfma_f32_16x16x32_bf16(qfL[1], kf[nt*2+1], a, 0, 0, 0);
        sAL[nt] = a;
    }
    {   // prefetch K tile 1 (qtH >= 16, so tile 1 always exists)
        #pragma unroll
        for (int i = 0; i < 8; i++)
            kf[i] = *(const bf16x8*)(Kt + (size_t)4096 + i * 512 + lane * 8);
    }

    for (int j = 0; j <= qtH; j += 2) {
        ATTN_ITER(j, sAH, sAL, sBH, sBL);
        if (j + 1 <= qtH)
            ATTN_ITER(j + 1, sBH, sBL, sAH, sAL);
    }

    // epilogue: l = lacc[r] (same in all 16 col-lanes), normalize, store bf16
    #pragma unroll
    for (int r = 0; r < 4; r++) {
        const float invH = 1.f / laccH[r];
        const float invL = 1.f / laccL[r];
        const int rowH = qrow0H + quad * 4 + r;
        const int rowL = qrow0L + quad * 4 + r;
        short* ypH = Y + (bT + rowH) * C_ + h * 64 + l15;
        short* ypL = Y + (bT + rowL) * C_ + h * 64 + l15;
        #pragma unroll
        for (int nt = 0; nt < 4; nt++) {
            ypH[nt * 16] = f2bf(OaccH[nt][r] * invH);
            ypL[nt * 16] = f2bf(OaccL[nt][r] * invL);
        }
    }
}

extern "C" void kernel_launch(void* const* d_in, const int* in_sizes, int n_in,
                              void* d_out, int out_size, void* d_ws, size_t ws_size,
                              hipStream_t stream) {
    const float* x  = (const float*)d_in[0];
    const float* Wq = (const float*)d_in[1];
    const float* Wk = (const float*)d_in[2];
    const float* Wv = (const float*)d_in[3];
    const float* Wo = (const float*)d_in[4];
    float* out = (float*)d_out;

    const int M = B_ * T_;                           // 4096
    short* xb  = (short*)d_ws;                       // [4096][1024]
    short* Wt  = xb  + (size_t)M * C_;               // [1536][1024]
    short* Wot = Wt  + (size_t)NQKV_ * C_;           // [1024][1024]
    short* QKV = Wot + (size_t)C_ * C_;              // [4096][1536]
    short* Yb  = QKV + (size_t)M * NQKV_;            // [4096][1024]
    short* Ktg = Yb  + (size_t)M * C_;               // [8][32][4096] frag-stream
    short* Vtg = Ktg + (size_t)8 * 32 * 4096;        // [8][32][4096] frag-stream

    cast_bf16<<<dim3(M * C_ / (256 * 8)), dim3(256), 0, stream>>>(x, xb, M * C_);
    w_transpose<<<dim3(32, 32, 4), dim3(32, 8), 0, stream>>>(Wq, Wk, Wv, Wo, Wt, Wot);

    gemm_bf16<true><<<dim3(NQKV_ / 128, M / 64), dim3(256), 0, stream>>>(
        xb, Wt, QKV, M, NQKV_, C_);
    kv_tile<<<dim3(32, 8), dim3(256), 0, stream>>>(QKV, Ktg, Vtg);
    attn_mfma<<<dim3(NQT_ / 2, B_ * H_), dim3(256), 0, stream>>>(QKV, Ktg, Vtg, Yb);
    gemm_bf16<false><<<dim3(C_ / 128, M / 64), dim3(256), 0, stream>>>(
        Yb, Wot, out, M, C_, C_);
}